// Round 6
// baseline (1600.105 us; speedup 1.0000x reference)
//
#include <hip/hip_runtime.h>
#include <hip/hip_bf16.h>

#define N_POINTS   2000000
#define NUM_GRAPHS 16384
#define HID        40
#define SLOPE      0.01f

// Fused kernel geometry: 1024 blocks x 4 waves x 4 graphs/wave = 16384 graphs.
// batch is SORTED -> each graph is a contiguous point range [start[g], start[g+1]).
// A wave owns its graphs end-to-end: emb FFN + aggregate (registers) -> global FFN
// (wave-level) -> out FFN (MFMA, verbatim fragment layout from the proven pass C)
// -> pool (quad shuffle-sum; all 64 pts same graph) -> disc head -> out[g].
// NO atomics, NO xe global round-trip, NO inter-kernel syncs.
// LEDGER: R1/R3 streamed pass A = GB-scale scratch traffic (watch FETCH/WRITE);
// R2 taught atomics need lockstep -> moot here (no atomics at all).
#define NB    1024
#define GPW   4      // graphs per wave
#define CAP   192    // LDS xe staging capacity per graph (mean 122, sd 11 -> 6.4 sigma;
                     // >CAP points fall back to recompute — correct for any input)
#define AROW  20     // dwords per bf16 h1 row (40 bf16)

typedef __attribute__((ext_vector_type(8))) short short8;
typedef __attribute__((ext_vector_type(4))) float fx4;

__device__ __forceinline__ float lrelu(float v) { return v > 0.f ? v : SLOPE * v; }
__device__ __forceinline__ unsigned short f2bf(float f) {
    __hip_bfloat16 h = __float2bfloat16(f);
    return *(unsigned short*)&h;
}
__device__ __forceinline__ float bf2f(unsigned short u) {
    unsigned int v = ((unsigned int)u) << 16;
    return __uint_as_float(v);
}

// ---------------- starts: start[g] = first i with batch[i] >= g; start[B] = N ----------------
__global__ __launch_bounds__(256) void k_starts(
    const int* __restrict__ batch, int* __restrict__ start)
{
    int i = blockIdx.x * 256 + threadIdx.x;
    if (i >= N_POINTS) return;
    int b = batch[i];
    if (i == 0) {
        for (int g = 0; g <= b; ++g) start[g] = 0;
    } else {
        int bp = batch[i - 1];
        for (int g = bp + 1; g <= b; ++g) start[g] = i;
    }
    if (i == N_POINTS - 1) {
        for (int g = b + 1; g <= NUM_GRAPHS; ++g) start[g] = N_POINTS;
    }
}

// ---------------- fused EPiC + disc, one wave per graph-group ----------------
__global__ __launch_bounds__(256, 4) void k_fused(
    const float* __restrict__ x, const int* __restrict__ start,
    const float* __restrict__ We1, const float* __restrict__ We2,
    const float* __restrict__ Wg1, const float* __restrict__ Wg2,
    const float* __restrict__ Wo1, const float* __restrict__ Wo2,
    const float* __restrict__ Wd1, const float* __restrict__ Wd2,
    float* __restrict__ out)
{
    __shared__ __align__(16) float sWe1[3 * HID];
    __shared__ __align__(16) float sWe2T[5 * HID];      // [c][j]
    __shared__ __align__(16) float sWg1[5 * HID];
    __shared__ __align__(16) float sWg2[HID * 4];
    __shared__ __align__(16) float sWo1[5 * HID];       // rows 0..4 (xe part)
    __shared__ __align__(16) float sWo1g[4 * HID];      // rows 5..8 (global part)
    __shared__ __align__(16) float sWd1T[HID * 32];     // [j][c]
    __shared__ __align__(16) float sWd2[HID];
    __shared__ __align__(16) float gcw[4][HID];         // per-wave g_contrib
    __shared__ __align__(16) float pld[4][32];          // per-wave pooled broadcast
    __shared__ unsigned short xeS[4][5][CAP];           // per-wave xe staging (bf16)
    __shared__ __align__(16) unsigned int h1S[4][64 * AROW];  // per-wave MFMA A-stage

    int tid = threadIdx.x;
    for (int k = tid; k < 3 * HID; k += 256) sWe1[k] = We1[k];
    for (int k = tid; k < 5 * HID; k += 256) sWe2T[k] = We2[(k % HID) * 5 + k / HID];
    for (int k = tid; k < 5 * HID; k += 256) sWg1[k] = Wg1[k];
    for (int k = tid; k < HID * 4; k += 256) sWg2[k] = Wg2[k];
    for (int k = tid; k < 5 * HID; k += 256) sWo1[k] = Wo1[k];
    for (int k = tid; k < 4 * HID; k += 256) sWo1g[k] = Wo1[5 * HID + k];
    for (int k = tid; k < 32 * HID; k += 256) sWd1T[k] = Wd1[(k % 32) * HID + k / 32];
    for (int k = tid; k < HID; k += 256) sWd2[k] = Wd2[k];

    int wid = tid >> 6, lane = tid & 63;
    int l16 = lane & 15, quad = lane >> 4;

    // B fragments (Wo2 -> bf16), verbatim from proven pass C
    short8 bfrag[2][2];
#pragma unroll
    for (int nt = 0; nt < 2; ++nt) {
#pragma unroll
        for (int ks = 0; ks < 2; ++ks) {
#pragma unroll
            for (int j = 0; j < 8; ++j) {
                int kk = ks * 32 + quad * 8 + j;
                float w = (kk < HID) ? Wo2[kk * 32 + nt * 16 + l16] : 0.f;
                bfrag[nt][ks][j] = (short)f2bf(w);
            }
        }
    }
    __syncthreads();   // weights visible; waves are independent hereafter

    int wslot = blockIdx.x * 4 + wid;

    for (int gi = 0; gi < GPW; ++gi) {
        int g = wslot * GPW + gi;
        int sg = start[g], eg = start[g + 1];
        int npts = eg - sg;
        int nr = (npts + 63) >> 6;

        // ---- pass 1: emb FFN per point, stage xe (bf16), accumulate graph sum ----
        float acc5[5] = {0.f, 0.f, 0.f, 0.f, 0.f};
        for (int r = 0; r < nr; ++r) {
            int idx = sg + r * 64 + lane;
            bool v = idx < eg;
            int ic = v ? idx : sg;
            float x0 = x[ic * 3 + 0], x1 = x[ic * 3 + 1], x2 = x[ic * 3 + 2];

            float h[HID];
            const float4* W1r = (const float4*)sWe1;
#pragma unroll
            for (int j4 = 0; j4 < HID / 4; ++j4) {
                float4 wa = W1r[j4], wb = W1r[10 + j4], wc = W1r[20 + j4];
                float wav[4] = {wa.x, wa.y, wa.z, wa.w};
                float wbv[4] = {wb.x, wb.y, wb.z, wb.w};
                float wcv[4] = {wc.x, wc.y, wc.z, wc.w};
#pragma unroll
                for (int k = 0; k < 4; ++k)
                    h[j4 * 4 + k] = lrelu(x0 * wav[k] + x1 * wbv[k] + x2 * wcv[k]);
            }
            int sp = r * 64 + lane;
#pragma unroll
            for (int c = 0; c < 5; ++c) {
                const float4* wr = (const float4*)&sWe2T[c * HID];
                float s = 0.f;
#pragma unroll
                for (int j4 = 0; j4 < HID / 4; ++j4) {
                    float4 w = wr[j4];
                    s += h[j4 * 4 + 0] * w.x + h[j4 * 4 + 1] * w.y + h[j4 * 4 + 2] * w.z + h[j4 * 4 + 3] * w.w;
                }
                float e = v ? lrelu(s) : 0.f;
                acc5[c] += e;
                if (sp < CAP) xeS[wid][c][sp] = f2bf(e);
            }
        }
        // wave-reduce the 5 channel sums (all lanes end with the total)
#pragma unroll
        for (int c = 0; c < 5; ++c) {
#pragma unroll
            for (int m = 1; m < 64; m <<= 1) acc5[c] += __shfl_xor(acc5[c], m);
        }

        // ---- global FFN (wave-level): lane j<40 owns hidden unit j ----
        float hg = 0.f;
        if (lane < HID) {
            float s = 0.f;
#pragma unroll
            for (int c = 0; c < 5; ++c) s += acc5[c] * sWg1[c * HID + lane];
            hg = lrelu(s);
        }
        float g4[4];
#pragma unroll
        for (int c = 0; c < 4; ++c) {
            float t = (lane < HID) ? hg * sWg2[lane * 4 + c] : 0.f;
#pragma unroll
            for (int m = 1; m < 64; m <<= 1) t += __shfl_xor(t, m);
            g4[c] = lrelu(t);
        }
        if (lane < HID) {
            float s = 0.f;
#pragma unroll
            for (int c = 0; c < 4; ++c) s += g4[c] * sWo1g[c * HID + lane];
            gcw[wid][lane] = s;     // in-wave DS ordering covers the read below
        }

        // ---- pass 2: h1 + MFMA (40->32) + dense pool (same graph for all 64 pts) ----
        float gpool[2] = {0.f, 0.f};
        short8 zfrag = {0, 0, 0, 0, 0, 0, 0, 0};
        for (int r = 0; r < nr; ++r) {
            int idx = sg + r * 64 + lane;
            bool v = idx < eg;
            int sp = r * 64 + lane;

            float xe[5];
            if (r * 64 + 63 < CAP || sp < CAP) {   // hot path (uniform for r<3)
#pragma unroll
                for (int c = 0; c < 5; ++c) xe[c] = bf2f(xeS[wid][c][sp < CAP ? sp : 0]);
            }
            if (sp >= CAP) {                        // cold fallback: recompute emb FFN
                int ic = v ? idx : sg;
                float x0 = x[ic * 3 + 0], x1 = x[ic * 3 + 1], x2 = x[ic * 3 + 2];
                float h[HID];
                const float4* W1r = (const float4*)sWe1;
#pragma unroll
                for (int j4 = 0; j4 < HID / 4; ++j4) {
                    float4 wa = W1r[j4], wb = W1r[10 + j4], wc = W1r[20 + j4];
                    float wav[4] = {wa.x, wa.y, wa.z, wa.w};
                    float wbv[4] = {wb.x, wb.y, wb.z, wb.w};
                    float wcv[4] = {wc.x, wc.y, wc.z, wc.w};
#pragma unroll
                    for (int k = 0; k < 4; ++k)
                        h[j4 * 4 + k] = lrelu(x0 * wav[k] + x1 * wbv[k] + x2 * wcv[k]);
                }
#pragma unroll
                for (int c = 0; c < 5; ++c) {
                    const float4* wr = (const float4*)&sWe2T[c * HID];
                    float s = 0.f;
#pragma unroll
                    for (int j4 = 0; j4 < HID / 4; ++j4) {
                        float4 w = wr[j4];
                        s += h[j4 * 4 + 0] * w.x + h[j4 * 4 + 1] * w.y + h[j4 * 4 + 2] * w.z + h[j4 * 4 + 3] * w.w;
                    }
                    xe[c] = lrelu(s);
                }
            }

            // h1 = lrelu(xe @ Wo1[0:5] + gc); pack bf16; stage A row (invalid -> zeros)
            const float4* gc4 = (const float4*)&gcw[wid][0];
            unsigned int* row = &h1S[wid][lane * AROW];
#pragma unroll
            for (int j4 = 0; j4 < HID / 4; ++j4) {
                float4 gv = gc4[j4];
                float sv[4] = {gv.x, gv.y, gv.z, gv.w};
#pragma unroll
                for (int c = 0; c < 5; ++c) {
                    float4 w = ((const float4*)&sWo1[c * HID])[j4];
                    float wvv[4] = {w.x, w.y, w.z, w.w};
#pragma unroll
                    for (int k = 0; k < 4; ++k) sv[k] += xe[c] * wvv[k];
                }
                __hip_bfloat162 q0 = __float22bfloat162_rn(make_float2(lrelu(sv[0]), lrelu(sv[1])));
                __hip_bfloat162 q1 = __float22bfloat162_rn(make_float2(lrelu(sv[2]), lrelu(sv[3])));
                uint2 u;
                u.x = v ? *(unsigned int*)&q0 : 0u;
                u.y = v ? *(unsigned int*)&q1 : 0u;
                *(uint2*)(row + j4 * 2) = u;
            }

            // MFMA verbatim: wave's 4 m-tiles x 2 ntiles; K = 32 + 8
#pragma unroll
            for (int m = 0; m < 4; ++m) {
                const unsigned int* arow = &h1S[wid][(m * 16 + l16) * AROW];
                short8 a0 = *(const short8*)(arow + quad * 4);
                short8 a1 = (quad == 0) ? *(const short8*)(arow + 16) : zfrag;
#pragma unroll
                for (int nt = 0; nt < 2; ++nt) {
                    fx4 acc = {0.f, 0.f, 0.f, 0.f};
                    acc = __builtin_amdgcn_mfma_f32_16x16x32_bf16(a0, bfrag[nt][0], acc, 0, 0, 0);
                    acc = __builtin_amdgcn_mfma_f32_16x16x32_bf16(a1, bfrag[nt][1], acc, 0, 0, 0);
                    // C layout: col = l16 = channel nt*16+l16; rows = points -> pool = sum rows
#pragma unroll
                    for (int rr = 0; rr < 4; ++rr) gpool[nt] += lrelu(acc[rr]);
                }
            }
        }
        // reduce pool over the quad groups (lanes sharing l16): full pooled[ch] everywhere
#pragma unroll
        for (int nt = 0; nt < 2; ++nt) {
            gpool[nt] += __shfl_xor(gpool[nt], 16);
            gpool[nt] += __shfl_xor(gpool[nt], 32);
        }
        if (quad == 0) {
            pld[wid][l16] = gpool[0];
            pld[wid][16 + l16] = gpool[1];
        }

        // ---- disc head: lane j<40 -> lrelu(pooled @ Wd1)[j] * Wd2[j], reduce ----
        float accd = 0.f;
        if (lane < HID) {
            const float4* pp = (const float4*)&pld[wid][0];
            const float4* wr = (const float4*)&sWd1T[lane * 32];
            float s = 0.f;
#pragma unroll
            for (int c4 = 0; c4 < 8; ++c4) {
                float4 w = wr[c4];
                float4 p = pp[c4];
                s += p.x * w.x + p.y * w.y + p.z * w.z + p.w * w.w;
            }
            accd = lrelu(s) * sWd2[lane];
        }
#pragma unroll
        for (int m = 1; m < 64; m <<= 1) accd += __shfl_xor(accd, m);
        if (lane == 0) out[g] = accd;
    }
}

extern "C" void kernel_launch(void* const* d_in, const int* in_sizes, int n_in,
                              void* d_out, int out_size, void* d_ws, size_t ws_size,
                              hipStream_t stream) {
    const float* x     = (const float*)d_in[0];
    const int*   batch = (const int*)  d_in[1];
    const float* We1   = (const float*)d_in[2];
    const float* We2   = (const float*)d_in[3];
    const float* Wg1   = (const float*)d_in[4];
    const float* Wg2   = (const float*)d_in[5];
    const float* Wo1   = (const float*)d_in[6];
    const float* Wo2   = (const float*)d_in[7];
    const float* Wd1   = (const float*)d_in[8];
    const float* Wd2   = (const float*)d_in[9];
    float* out = (float*)d_out;

    int* start = (int*)d_ws;   // (NUM_GRAPHS+1) ints

    k_starts<<<(N_POINTS + 255) / 256, 256, 0, stream>>>(batch, start);
    k_fused<<<NB, 256, 0, stream>>>(x, start, We1, We2, Wg1, Wg2,
                                    Wo1, Wo2, Wd1, Wd2, out);
}

// Round 7
// 987.627 us; speedup vs baseline: 1.6202x; 1.6202x over previous
//
#include <hip/hip_runtime.h>
#include <hip/hip_bf16.h>

#define N_POINTS   2000000
#define NUM_GRAPHS 16384
#define HID        40
#define SLOPE      0.01f

// Fused kernel: 1024 blocks x 4 waves x 4 graphs/wave = 16384 graphs.
// batch is SORTED -> graph g owns the contiguous range [start[g], start[g+1]).
// Wave-owned end-to-end: emb FFN + register aggregate -> wave-level global FFN ->
// MFMA out-FFN (proven fragment layout) -> quad-shuffle pool -> disc head.
// No atomics, no xe round-trip, no inter-kernel syncs, no memset.
//
// LEDGER (GB-traffic disease, R1/R3/R6): the emb-FFN h[40] body SPILLS TO SCRATCH
// when compiled hot under a 128-reg budget with extra live state (bfrag/acc5);
// scratch thrash = 2.2+2.4 GB phantom HBM traffic, kernel goes BW-bound on it.
// R0 pass A proved the same body is spill-free at __launch_bounds__(256,2).
// Fixes here: (256,2) budget + bfrag rebuilt per-graph from LDS (live range =
// pass 2 only) + cold path uses streamed 5-accumulator form (no h[40] in pass 2).
// CANARY: FETCH must be ~35 MB. GB-scale => spill came back.
#define NB    1024
#define GPW   4      // graphs per wave
#define CAP   192    // xe staging capacity per graph (mean 122, sd 11; overflow -> recompute)
#define AROW  20     // dwords per bf16 h1 row (40 bf16)

typedef __attribute__((ext_vector_type(8))) short short8;
typedef __attribute__((ext_vector_type(4))) float fx4;

__device__ __forceinline__ float lrelu(float v) { return v > 0.f ? v : SLOPE * v; }
__device__ __forceinline__ unsigned short f2bf(float f) {
    __hip_bfloat16 h = __float2bfloat16(f);
    return *(unsigned short*)&h;
}
__device__ __forceinline__ float bf2f(unsigned short u) {
    unsigned int v = ((unsigned int)u) << 16;
    return __uint_as_float(v);
}

// ---------------- starts: start[g] = first i with batch[i] >= g; start[B] = N ----------------
__global__ __launch_bounds__(256) void k_starts(
    const int* __restrict__ batch, int* __restrict__ start)
{
    int i = blockIdx.x * 256 + threadIdx.x;
    if (i >= N_POINTS) return;
    int b = batch[i];
    if (i == 0) {
        for (int g = 0; g <= b; ++g) start[g] = 0;
    } else {
        int bp = batch[i - 1];
        for (int g = bp + 1; g <= b; ++g) start[g] = i;
    }
    if (i == N_POINTS - 1) {
        for (int g = b + 1; g <= NUM_GRAPHS; ++g) start[g] = N_POINTS;
    }
}

// ---------------- fused EPiC + disc, one wave per graph-group ----------------
__global__ __launch_bounds__(256, 2) void k_fused(
    const float* __restrict__ x, const int* __restrict__ start,
    const float* __restrict__ We1, const float* __restrict__ We2,
    const float* __restrict__ Wg1, const float* __restrict__ Wg2,
    const float* __restrict__ Wo1, const float* __restrict__ Wo2,
    const float* __restrict__ Wd1, const float* __restrict__ Wd2,
    float* __restrict__ out)
{
    __shared__ __align__(16) float sWe1[3 * HID];
    __shared__ __align__(16) float sWe2T[5 * HID];      // [c][j]
    __shared__ __align__(16) float sWg1[5 * HID];
    __shared__ __align__(16) float sWg2[HID * 4];
    __shared__ __align__(16) float sWo1[5 * HID];       // rows 0..4 (xe part)
    __shared__ __align__(16) float sWo1g[4 * HID];      // rows 5..8 (global part)
    __shared__ __align__(16) float sWo2[HID * 32];      // for per-graph bfrag rebuild
    __shared__ __align__(16) float sWd1T[HID * 32];     // [j][c]
    __shared__ __align__(16) float sWd2[HID];
    __shared__ __align__(16) float gcw[4][HID];         // per-wave g_contrib
    __shared__ __align__(16) float pld[4][32];          // per-wave pooled broadcast
    __shared__ unsigned short xeS[4][5][CAP];           // per-wave xe staging (bf16)
    __shared__ __align__(16) unsigned int h1S[4][64 * AROW];  // per-wave MFMA A-stage

    int tid = threadIdx.x;
    for (int k = tid; k < 3 * HID; k += 256) sWe1[k] = We1[k];
    for (int k = tid; k < 5 * HID; k += 256) sWe2T[k] = We2[(k % HID) * 5 + k / HID];
    for (int k = tid; k < 5 * HID; k += 256) sWg1[k] = Wg1[k];
    for (int k = tid; k < HID * 4; k += 256) sWg2[k] = Wg2[k];
    for (int k = tid; k < 5 * HID; k += 256) sWo1[k] = Wo1[k];
    for (int k = tid; k < 4 * HID; k += 256) sWo1g[k] = Wo1[5 * HID + k];
    for (int k = tid; k < HID * 32; k += 256) sWo2[k] = Wo2[k];
    for (int k = tid; k < 32 * HID; k += 256) sWd1T[k] = Wd1[(k % 32) * HID + k / 32];
    for (int k = tid; k < HID; k += 256) sWd2[k] = Wd2[k];

    int wid = tid >> 6, lane = tid & 63;
    int l16 = lane & 15, quad = lane >> 4;

    __syncthreads();   // weights visible; waves are independent hereafter

    int wslot = blockIdx.x * 4 + wid;

    for (int gi = 0; gi < GPW; ++gi) {
        int g = wslot * GPW + gi;
        int sg = start[g], eg = start[g + 1];
        int npts = eg - sg;
        int nr = (npts + 63) >> 6;

        // ---- pass 1: emb FFN per point, stage xe (bf16), accumulate graph sum ----
        float acc5[5] = {0.f, 0.f, 0.f, 0.f, 0.f};
        for (int r = 0; r < nr; ++r) {
            int idx = sg + r * 64 + lane;
            bool v = idx < eg;
            int ic = v ? idx : sg;
            float x0 = x[ic * 3 + 0], x1 = x[ic * 3 + 1], x2 = x[ic * 3 + 2];

            float h[HID];
            const float4* W1r = (const float4*)sWe1;
#pragma unroll
            for (int j4 = 0; j4 < HID / 4; ++j4) {
                float4 wa = W1r[j4], wb = W1r[10 + j4], wc = W1r[20 + j4];
                float wav[4] = {wa.x, wa.y, wa.z, wa.w};
                float wbv[4] = {wb.x, wb.y, wb.z, wb.w};
                float wcv[4] = {wc.x, wc.y, wc.z, wc.w};
#pragma unroll
                for (int k = 0; k < 4; ++k)
                    h[j4 * 4 + k] = lrelu(x0 * wav[k] + x1 * wbv[k] + x2 * wcv[k]);
            }
            int sp = r * 64 + lane;
#pragma unroll
            for (int c = 0; c < 5; ++c) {
                const float4* wr = (const float4*)&sWe2T[c * HID];
                float s = 0.f;
#pragma unroll
                for (int j4 = 0; j4 < HID / 4; ++j4) {
                    float4 w = wr[j4];
                    s += h[j4 * 4 + 0] * w.x + h[j4 * 4 + 1] * w.y + h[j4 * 4 + 2] * w.z + h[j4 * 4 + 3] * w.w;
                }
                float e = v ? lrelu(s) : 0.f;
                acc5[c] += e;
                if (sp < CAP) xeS[wid][c][sp] = f2bf(e);
            }
        }
        // wave-reduce the 5 channel sums (all lanes end with the total)
#pragma unroll
        for (int c = 0; c < 5; ++c) {
#pragma unroll
            for (int m = 1; m < 64; m <<= 1) acc5[c] += __shfl_xor(acc5[c], m);
        }

        // ---- global FFN (wave-level): lane j<40 owns hidden unit j ----
        float hg = 0.f;
        if (lane < HID) {
            float s = 0.f;
#pragma unroll
            for (int c = 0; c < 5; ++c) s += acc5[c] * sWg1[c * HID + lane];
            hg = lrelu(s);
        }
        float g4[4];
#pragma unroll
        for (int c = 0; c < 4; ++c) {
            float t = (lane < HID) ? hg * sWg2[lane * 4 + c] : 0.f;
#pragma unroll
            for (int m = 1; m < 64; m <<= 1) t += __shfl_xor(t, m);
            g4[c] = lrelu(t);
        }
        if (lane < HID) {
            float s = 0.f;
#pragma unroll
            for (int c = 0; c < 4; ++c) s += g4[c] * sWo1g[c * HID + lane];
            gcw[wid][lane] = s;     // in-wave DS ordering covers the read below
        }

        // ---- bfrag rebuilt here: live range = pass 2 only (spill-pressure fix) ----
        short8 bfrag[2][2];
#pragma unroll
        for (int nt = 0; nt < 2; ++nt) {
#pragma unroll
            for (int ks = 0; ks < 2; ++ks) {
#pragma unroll
                for (int j = 0; j < 8; ++j) {
                    int kk = ks * 32 + quad * 8 + j;
                    float w = (kk < HID) ? sWo2[kk * 32 + nt * 16 + l16] : 0.f;
                    bfrag[nt][ks][j] = (short)f2bf(w);
                }
            }
        }
        short8 zfrag = {0, 0, 0, 0, 0, 0, 0, 0};

        // ---- pass 2: h1 + MFMA (40->32) + dense pool (all 64 pts same graph) ----
        float gpool[2] = {0.f, 0.f};
        for (int r = 0; r < nr; ++r) {
            int idx = sg + r * 64 + lane;
            bool v = idx < eg;
            int sp = r * 64 + lane;

            float xe[5];
            if (sp < CAP) {
#pragma unroll
                for (int c = 0; c < 5; ++c) xe[c] = bf2f(xeS[wid][c][sp]);
            } else {
                // cold overflow path (p ~ 1e-10/graph): streamed recompute, NO h[40]
                int ic = v ? idx : sg;
                float x0 = x[ic * 3 + 0], x1 = x[ic * 3 + 1], x2 = x[ic * 3 + 2];
                float s5[5] = {0.f, 0.f, 0.f, 0.f, 0.f};
                for (int j = 0; j < HID; ++j) {
                    float h = lrelu(x0 * sWe1[j] + x1 * sWe1[HID + j] + x2 * sWe1[2 * HID + j]);
#pragma unroll
                    for (int c = 0; c < 5; ++c) s5[c] += h * sWe2T[c * HID + j];
                }
#pragma unroll
                for (int c = 0; c < 5; ++c) xe[c] = lrelu(s5[c]);
            }

            // h1 = lrelu(xe @ Wo1[0:5] + gc); pack bf16; stage A row (invalid -> zeros)
            const float4* gc4 = (const float4*)&gcw[wid][0];
            unsigned int* row = &h1S[wid][lane * AROW];
#pragma unroll
            for (int j4 = 0; j4 < HID / 4; ++j4) {
                float4 gv = gc4[j4];
                float sv[4] = {gv.x, gv.y, gv.z, gv.w};
#pragma unroll
                for (int c = 0; c < 5; ++c) {
                    float4 w = ((const float4*)&sWo1[c * HID])[j4];
                    float wvv[4] = {w.x, w.y, w.z, w.w};
#pragma unroll
                    for (int k = 0; k < 4; ++k) sv[k] += xe[c] * wvv[k];
                }
                __hip_bfloat162 q0 = __float22bfloat162_rn(make_float2(lrelu(sv[0]), lrelu(sv[1])));
                __hip_bfloat162 q1 = __float22bfloat162_rn(make_float2(lrelu(sv[2]), lrelu(sv[3])));
                uint2 u;
                u.x = v ? *(unsigned int*)&q0 : 0u;
                u.y = v ? *(unsigned int*)&q1 : 0u;
                *(uint2*)(row + j4 * 2) = u;
            }

            // MFMA verbatim (proven layout): wave's 4 m-tiles x 2 ntiles; K = 32 + 8
#pragma unroll
            for (int m = 0; m < 4; ++m) {
                const unsigned int* arow = &h1S[wid][(m * 16 + l16) * AROW];
                short8 a0 = *(const short8*)(arow + quad * 4);
                short8 a1 = (quad == 0) ? *(const short8*)(arow + 16) : zfrag;
#pragma unroll
                for (int nt = 0; nt < 2; ++nt) {
                    fx4 acc = {0.f, 0.f, 0.f, 0.f};
                    acc = __builtin_amdgcn_mfma_f32_16x16x32_bf16(a0, bfrag[nt][0], acc, 0, 0, 0);
                    acc = __builtin_amdgcn_mfma_f32_16x16x32_bf16(a1, bfrag[nt][1], acc, 0, 0, 0);
                    // C layout: col = l16 = channel nt*16+l16; rows = points -> pool = sum rows
#pragma unroll
                    for (int rr = 0; rr < 4; ++rr) gpool[nt] += lrelu(acc[rr]);
                }
            }
        }
        // reduce pool over quad groups (lanes sharing l16)
#pragma unroll
        for (int nt = 0; nt < 2; ++nt) {
            gpool[nt] += __shfl_xor(gpool[nt], 16);
            gpool[nt] += __shfl_xor(gpool[nt], 32);
        }
        if (quad == 0) {
            pld[wid][l16] = gpool[0];
            pld[wid][16 + l16] = gpool[1];
        }

        // ---- disc head: lane j<40 -> lrelu(pooled @ Wd1)[j] * Wd2[j], reduce ----
        float accd = 0.f;
        if (lane < HID) {
            const float4* pp = (const float4*)&pld[wid][0];
            const float4* wr = (const float4*)&sWd1T[lane * 32];
            float s = 0.f;
#pragma unroll
            for (int c4 = 0; c4 < 8; ++c4) {
                float4 w = wr[c4];
                float4 p = pp[c4];
                s += p.x * w.x + p.y * w.y + p.z * w.z + p.w * w.w;
            }
            accd = lrelu(s) * sWd2[lane];
        }
#pragma unroll
        for (int m = 1; m < 64; m <<= 1) accd += __shfl_xor(accd, m);
        if (lane == 0) out[g] = accd;
    }
}

extern "C" void kernel_launch(void* const* d_in, const int* in_sizes, int n_in,
                              void* d_out, int out_size, void* d_ws, size_t ws_size,
                              hipStream_t stream) {
    const float* x     = (const float*)d_in[0];
    const int*   batch = (const int*)  d_in[1];
    const float* We1   = (const float*)d_in[2];
    const float* We2   = (const float*)d_in[3];
    const float* Wg1   = (const float*)d_in[4];
    const float* Wg2   = (const float*)d_in[5];
    const float* Wo1   = (const float*)d_in[6];
    const float* Wo2   = (const float*)d_in[7];
    const float* Wd1   = (const float*)d_in[8];
    const float* Wd2   = (const float*)d_in[9];
    float* out = (float*)d_out;

    int* start = (int*)d_ws;   // (NUM_GRAPHS+1) ints

    k_starts<<<(N_POINTS + 255) / 256, 256, 0, stream>>>(batch, start);
    k_fused<<<NB, 256, 0, stream>>>(x, start, We1, We2, Wg1, Wg2,
                                    Wo1, Wo2, Wd1, Wd2, out);
}

// Round 9
// 578.600 us; speedup vs baseline: 2.7655x; 1.7069x over previous
//
#include <hip/hip_runtime.h>
#include <hip/hip_bf16.h>

#define N_POINTS   2000000
#define NUM_GRAPHS 16384
#define HID        40
#define SLOPE      0.01f

// Pass A tiling: 256 pts/block, 1 pt/thread (R5-proven healthy)
#define TILE_A     256
#define NT_A       ((N_POINTS + TILE_A - 1) / TILE_A)   // 7813
#define XESA       288    // dwords per xeT channel row

// Graph-owned back half: 1024 blocks x 4 waves x 4 graphs = 16384 graphs
#define NB    1024
#define GPW   4
#define AROW  20     // dwords per bf16 h1 row (40 bf16)

// LEDGER (cross-round, do not relearn):
//  - R1/R3/R6/R7: any LARGE kernel containing the emb-FFN h[40] body spills to
//    scratch (GB-scale FETCH/WRITE, BW-bound at 2-3 TB/s). R7 proved it persists
//    even at VGPR=128 budget -> structural (unroller/allocator failure in big
//    bodies), not a simple budget issue. FIX: keep kernels SMALL; the same body
//    compiles clean in R0/R5-sized kernels. CANARY: WRITE_SIZE >> real stores.
//  - R2: pooled atomics need temporally-clustered (lockstep) issue or L2
//    write-combining dies (WRITE 21->303MB). Moot in graph-owned pool (no atomics).
//  - R4: register prefetch of batch/xe = neutral; front-end latency isn't exposed.
//  - R8: container failure, kernel never ran; this is a byte-identical resubmit.

typedef __attribute__((ext_vector_type(8))) short short8;
typedef __attribute__((ext_vector_type(4))) float fx4;

__device__ __forceinline__ float lrelu(float v) { return v > 0.f ? v : SLOPE * v; }
__device__ __forceinline__ int padidx(int p) { return p + ((p >> 5) << 2); }
__device__ __forceinline__ unsigned short f2bf(float f) {
    __hip_bfloat16 h = __float2bfloat16(f);
    return *(unsigned short*)&h;
}
__device__ __forceinline__ float bf2f(unsigned short u) {
    unsigned int v = ((unsigned int)u) << 16;
    return __uint_as_float(v);
}

// ---------------- starts: start[g] = first i with batch[i] >= g; start[B] = N ----------------
__global__ __launch_bounds__(256) void k_starts(
    const int* __restrict__ batch, int* __restrict__ start)
{
    int i = blockIdx.x * 256 + threadIdx.x;
    if (i >= N_POINTS) return;
    int b = batch[i];
    if (i == 0) {
        for (int g = 0; g <= b; ++g) start[g] = 0;
    } else {
        int bp = batch[i - 1];
        for (int g = bp + 1; g <= b; ++g) start[g] = i;
    }
    if (i == N_POINTS - 1) {
        for (int g = b + 1; g <= NUM_GRAPHS; ++g) start[g] = N_POINTS;
    }
}

// ---------------- Pass A: emb FFN (1 pt/thread) + transpose-reduce + xe bf16 cache ----------------
// R5-proven verbatim.
__global__ __launch_bounds__(256, 4) void k_emb_aggr(
    const float* __restrict__ x, const int* __restrict__ batch,
    const float* __restrict__ We1, const float* __restrict__ We2,
    float* __restrict__ x_aggr, unsigned short* __restrict__ xe_out, int use_xe)
{
    __shared__ __align__(16) float sWe1[3 * HID];
    __shared__ __align__(16) float sWe2T[5 * HID];          // [c][j]
    __shared__ __align__(16) float xeT[5 * XESA];           // chunk-padded
    __shared__ __align__(16) int   sbp[XESA];

    int tid = threadIdx.x;
    for (int k = tid; k < 3 * HID; k += 256) sWe1[k] = We1[k];
    for (int k = tid; k < 5 * HID; k += 256) sWe2T[k] = We2[(k % HID) * 5 + k / HID];
    __syncthreads();

    int p = blockIdx.x * TILE_A + tid;
    bool v = p < N_POINTS;
    int ic = v ? p : (N_POINTS - 1);
    float x0 = x[ic * 3 + 0], x1 = x[ic * 3 + 1], x2 = x[ic * 3 + 2];
    int b = v ? batch[ic] : -1;
    sbp[padidx(tid)] = b;

    float h[HID];
    const float4* W1r = (const float4*)sWe1;
#pragma unroll
    for (int j4 = 0; j4 < HID / 4; ++j4) {
        float4 wa = W1r[j4], wb = W1r[10 + j4], wc = W1r[20 + j4];
        float wav[4] = {wa.x, wa.y, wa.z, wa.w};
        float wbv[4] = {wb.x, wb.y, wb.z, wb.w};
        float wcv[4] = {wc.x, wc.y, wc.z, wc.w};
#pragma unroll
        for (int k = 0; k < 4; ++k)
            h[j4 * 4 + k] = lrelu(x0 * wav[k] + x1 * wbv[k] + x2 * wcv[k]);
    }

#pragma unroll
    for (int c = 0; c < 5; ++c) {
        const float4* wr = (const float4*)&sWe2T[c * HID];
        float s = 0.f;
#pragma unroll
        for (int j4 = 0; j4 < HID / 4; ++j4) {
            float4 w = wr[j4];
            s += h[j4 * 4 + 0] * w.x + h[j4 * 4 + 1] * w.y + h[j4 * 4 + 2] * w.z + h[j4 * 4 + 3] * w.w;
        }
        float e = v ? lrelu(s) : 0.f;
        xeT[c * XESA + padidx(tid)] = e;
        if (use_xe && v) xe_out[(size_t)c * N_POINTS + p] = f2bf(e);
    }
    __syncthreads();

    if (tid < 40) {
        int ch = tid >> 3, chunk = tid & 7;
        float acc = 0.f;
        int cur = sbp[chunk * 36];
#pragma unroll
        for (int g = 0; g < 8; ++g) {
            float4 v4 = *(const float4*)&xeT[ch * XESA + chunk * 36 + g * 4];
            int4   n4 = *(const int4*)&sbp[chunk * 36 + g * 4];
            float vv[4] = {v4.x, v4.y, v4.z, v4.w};
            int   nn[4] = {n4.x, n4.y, n4.z, n4.w};
#pragma unroll
            for (int k = 0; k < 4; ++k) {
                if (nn[k] != cur) {
                    if (cur >= 0) atomicAdd(&x_aggr[cur * 5 + ch], acc);
                    cur = nn[k];
                    acc = vv[k];
                } else {
                    acc += vv[k];
                }
            }
        }
        if (cur >= 0) atomicAdd(&x_aggr[cur * 5 + ch], acc);
    }
}

// ---------------- Pass B: per-graph global FFN + fold into W_out1 rows 5..8 ----------------
__global__ __launch_bounds__(256) void k_global(
    const float* __restrict__ x_aggr,
    const float* __restrict__ Wg1, const float* __restrict__ Wg2,
    const float* __restrict__ Wo1,
    float* __restrict__ g_contrib)
{
    __shared__ float sWg1[5 * HID];
    __shared__ float sWg2[HID * 4];
    __shared__ float sWo1g[4 * HID];
    for (int k = threadIdx.x; k < 5 * HID; k += 256) sWg1[k] = Wg1[k];
    for (int k = threadIdx.x; k < HID * 4; k += 256) sWg2[k] = Wg2[k];
    for (int k = threadIdx.x; k < 4 * HID; k += 256) sWo1g[k] = Wo1[5 * HID + k];
    __syncthreads();

    int bg = blockIdx.x * 256 + threadIdx.x;
    if (bg >= NUM_GRAPHS) return;

    float a[5];
#pragma unroll
    for (int c = 0; c < 5; ++c) a[c] = x_aggr[bg * 5 + c];

    float h[HID];
#pragma unroll
    for (int j = 0; j < HID; ++j) {
        float s = 0.f;
#pragma unroll
        for (int c = 0; c < 5; ++c) s += a[c] * sWg1[c * HID + j];
        h[j] = lrelu(s);
    }
    float g[4];
#pragma unroll
    for (int c = 0; c < 4; ++c) {
        float s = 0.f;
#pragma unroll
        for (int j = 0; j < HID; ++j) s += h[j] * sWg2[j * 4 + c];
        g[c] = lrelu(s);
    }
#pragma unroll
    for (int j = 0; j < HID; ++j) {
        float s = 0.f;
#pragma unroll
        for (int c = 0; c < 4; ++c) s += g[c] * sWo1g[c * HID + j];
        g_contrib[bg * HID + j] = s;
    }
}

// ---------------- Pass C': graph-owned out-FFN + dense pool + disc head ----------------
// batch sorted -> graph g = contiguous [start[g], start[g+1]). Wave owns GPW graphs:
// per 64-pt round: xe loads -> h1 VALU (proven block) -> wave-private h1S stage ->
// MFMA 4m x 2nt (proven fragment layout) -> accumulate lrelu into gpool (ALL 64 pts
// same graph -> dense sum, NO run-length scan, NO atomics) -> quad shuffle -> disc
// head -> out[g]. No barriers in main loop (wave-private LDS, R5-proven ordering).
// Small kernel on purpose: see LEDGER re: spill disease in large bodies.
__global__ __launch_bounds__(256, 4) void k_out_disc(
    const int* __restrict__ start,
    const float* __restrict__ x,
    const float* __restrict__ We1, const float* __restrict__ We2,
    const float* __restrict__ Wo1, const float* __restrict__ Wo2,
    const float* __restrict__ Wd1, const float* __restrict__ Wd2,
    const float* __restrict__ g_contrib,
    const unsigned short* __restrict__ xe_in, int use_xe,
    float* __restrict__ out)
{
    __shared__ __align__(16) float sWo1[5 * HID];
    __shared__ __align__(16) float sWd1T[HID * 32];     // [j][c]
    __shared__ __align__(16) float sWd2[HID];
    __shared__ __align__(16) float sWe1[3 * HID];       // cold path only
    __shared__ __align__(16) float sWe2T[5 * HID];      // cold path only
    __shared__ __align__(16) float pld[4][32];
    __shared__ __align__(16) unsigned int h1S[4][64 * AROW];

    int tid = threadIdx.x;
    for (int k = tid; k < 5 * HID; k += 256) sWo1[k] = Wo1[k];
    for (int k = tid; k < 32 * HID; k += 256) sWd1T[k] = Wd1[(k % 32) * HID + k / 32];
    for (int k = tid; k < HID; k += 256) sWd2[k] = Wd2[k];
    for (int k = tid; k < 3 * HID; k += 256) sWe1[k] = We1[k];
    for (int k = tid; k < 5 * HID; k += 256) sWe2T[k] = We2[(k % HID) * 5 + k / HID];

    int wid = tid >> 6, lane = tid & 63;
    int l16 = lane & 15, quad = lane >> 4;

    // B fragments (Wo2 -> bf16), proven layout, built once
    short8 bfrag[2][2];
#pragma unroll
    for (int nt = 0; nt < 2; ++nt) {
#pragma unroll
        for (int ks = 0; ks < 2; ++ks) {
#pragma unroll
            for (int j = 0; j < 8; ++j) {
                int kk = ks * 32 + quad * 8 + j;
                float w = (kk < HID) ? Wo2[kk * 32 + nt * 16 + l16] : 0.f;
                bfrag[nt][ks][j] = (short)f2bf(w);
            }
        }
    }
    short8 zfrag = {0, 0, 0, 0, 0, 0, 0, 0};
    __syncthreads();   // weights visible; waves independent hereafter

    int wslot = blockIdx.x * 4 + wid;

    for (int gi = 0; gi < GPW; ++gi) {
        int g = wslot * GPW + gi;
        int sg = start[g], eg = start[g + 1];
        int nr = (eg - sg + 63) >> 6;

        const float4* gc4 = (const float4*)(g_contrib + (size_t)g * HID);  // wave-uniform
        float gpool[2] = {0.f, 0.f};

        for (int r = 0; r < nr; ++r) {
            int idx = sg + r * 64 + lane;
            bool v = idx < eg;
            int ic = v ? idx : sg;

            float xe[5];
            if (use_xe) {
#pragma unroll
                for (int c = 0; c < 5; ++c) xe[c] = bf2f(xe_in[(size_t)c * N_POINTS + ic]);
            } else {
                // cold fallback (never taken with adequate ws): streamed, no h[40]
                float x0 = x[ic * 3 + 0], x1 = x[ic * 3 + 1], x2 = x[ic * 3 + 2];
                float s5[5] = {0.f, 0.f, 0.f, 0.f, 0.f};
                for (int j = 0; j < HID; ++j) {
                    float h = lrelu(x0 * sWe1[j] + x1 * sWe1[HID + j] + x2 * sWe1[2 * HID + j]);
#pragma unroll
                    for (int c = 0; c < 5; ++c) s5[c] += h * sWe2T[c * HID + j];
                }
#pragma unroll
                for (int c = 0; c < 5; ++c) xe[c] = lrelu(s5[c]);
            }

            // h1 = lrelu(xe @ Wo1[0:5] + g_contrib[g]); pack bf16; stage (invalid -> 0)
            unsigned int* row = &h1S[wid][lane * AROW];
#pragma unroll
            for (int j4 = 0; j4 < HID / 4; ++j4) {
                float4 gv = gc4[j4];
                float sv[4] = {gv.x, gv.y, gv.z, gv.w};
#pragma unroll
                for (int c = 0; c < 5; ++c) {
                    float4 w = ((const float4*)&sWo1[c * HID])[j4];
                    float wvv[4] = {w.x, w.y, w.z, w.w};
#pragma unroll
                    for (int k = 0; k < 4; ++k) sv[k] += xe[c] * wvv[k];
                }
                __hip_bfloat162 q0 = __float22bfloat162_rn(make_float2(lrelu(sv[0]), lrelu(sv[1])));
                __hip_bfloat162 q1 = __float22bfloat162_rn(make_float2(lrelu(sv[2]), lrelu(sv[3])));
                uint2 u;
                u.x = v ? *(unsigned int*)&q0 : 0u;
                u.y = v ? *(unsigned int*)&q1 : 0u;
                *(uint2*)(row + j4 * 2) = u;
            }

            // MFMA (proven layout): 4 m-tiles x 2 ntiles; K = 32 + 8
#pragma unroll
            for (int m = 0; m < 4; ++m) {
                const unsigned int* arow = &h1S[wid][(m * 16 + l16) * AROW];
                short8 a0 = *(const short8*)(arow + quad * 4);
                short8 a1 = (quad == 0) ? *(const short8*)(arow + 16) : zfrag;
#pragma unroll
                for (int nt = 0; nt < 2; ++nt) {
                    fx4 acc = {0.f, 0.f, 0.f, 0.f};
                    acc = __builtin_amdgcn_mfma_f32_16x16x32_bf16(a0, bfrag[nt][0], acc, 0, 0, 0);
                    acc = __builtin_amdgcn_mfma_f32_16x16x32_bf16(a1, bfrag[nt][1], acc, 0, 0, 0);
                    // C layout: col = l16 = channel; rows = points -> dense pool = sum rows
#pragma unroll
                    for (int rr = 0; rr < 4; ++rr) gpool[nt] += lrelu(acc[rr]);
                }
            }
        }

        // pool over quad groups (lanes sharing l16): 64 pts x all rounds summed
#pragma unroll
        for (int nt = 0; nt < 2; ++nt) {
            gpool[nt] += __shfl_xor(gpool[nt], 16);
            gpool[nt] += __shfl_xor(gpool[nt], 32);
        }
        if (quad == 0) {
            pld[wid][l16] = gpool[0];
            pld[wid][16 + l16] = gpool[1];
        }

        // disc head: lane j<40 -> lrelu(pooled @ Wd1)[j] * Wd2[j], wave-reduce
        float accd = 0.f;
        if (lane < HID) {
            const float4* pp = (const float4*)&pld[wid][0];
            const float4* wr = (const float4*)&sWd1T[lane * 32];
            float s = 0.f;
#pragma unroll
            for (int c4 = 0; c4 < 8; ++c4) {
                float4 w = wr[c4];
                float4 p = pp[c4];
                s += p.x * w.x + p.y * w.y + p.z * w.z + p.w * w.w;
            }
            accd = lrelu(s) * sWd2[lane];
        }
#pragma unroll
        for (int m = 1; m < 64; m <<= 1) accd += __shfl_xor(accd, m);
        if (lane == 0) out[g] = accd;
    }
}

extern "C" void kernel_launch(void* const* d_in, const int* in_sizes, int n_in,
                              void* d_out, int out_size, void* d_ws, size_t ws_size,
                              hipStream_t stream) {
    const float* x     = (const float*)d_in[0];
    const int*   batch = (const int*)  d_in[1];
    const float* We1   = (const float*)d_in[2];
    const float* We2   = (const float*)d_in[3];
    const float* Wg1   = (const float*)d_in[4];
    const float* Wg2   = (const float*)d_in[5];
    const float* Wo1   = (const float*)d_in[6];
    const float* Wo2   = (const float*)d_in[7];
    const float* Wd1   = (const float*)d_in[8];
    const float* Wd2   = (const float*)d_in[9];
    float* out = (float*)d_out;

    // ws layout: [x_aggr B*5][g_contrib B*40][start B+1][xe bf16 planar 5*N]
    float* x_aggr    = (float*)d_ws;
    float* g_contrib = x_aggr + NUM_GRAPHS * 5;
    int*   start     = (int*)(g_contrib + NUM_GRAPHS * HID);
    size_t head_bytes = (size_t)NUM_GRAPHS * (5 + HID) * sizeof(float)
                      + (NUM_GRAPHS + 1) * sizeof(int);
    unsigned short* xe_ws = (unsigned short*)((char*)d_ws + ((head_bytes + 15) & ~(size_t)15));
    size_t need = ((head_bytes + 15) & ~(size_t)15) + (size_t)N_POINTS * 5 * sizeof(unsigned short);
    int use_xe = (ws_size >= need) ? 1 : 0;

    hipMemsetAsync(x_aggr, 0, (size_t)NUM_GRAPHS * 5 * sizeof(float), stream);

    int gblk = (NUM_GRAPHS + 255) / 256;
    k_starts  <<<(N_POINTS + 255) / 256, 256, 0, stream>>>(batch, start);
    k_emb_aggr<<<NT_A, 256, 0, stream>>>(x, batch, We1, We2, x_aggr, xe_ws, use_xe);
    k_global  <<<gblk, 256, 0, stream>>>(x_aggr, Wg1, Wg2, Wo1, g_contrib);
    k_out_disc<<<NB, 256, 0, stream>>>(start, x, We1, We2, Wo1, Wo2, Wd1, Wd2,
                                       g_contrib, xe_ws, use_xe, out);
}